// Round 7
// baseline (279.856 us; speedup 1.0000x reference)
//
#include <hip/hip_runtime.h>
#include <math.h>

#define NB_B 2
#define NB_N 4096
#define NB_DIM 1024
#define NB_H 16
#define NB_D 64
#define NB_CTX 3072
#define NSPLIT 4
// 0.125 * log2(e): folds softmax base-2 conversion into q scale
#define QSCALE 0.18033688011112042f
#define NEGF -3.0e38f

typedef __attribute__((ext_vector_type(8))) short short8;
typedef __attribute__((ext_vector_type(4))) short s4v;
typedef __attribute__((ext_vector_type(4))) float f32x4;

#if __has_builtin(__builtin_amdgcn_mfma_f32_16x16x16bf16_1k)
__device__ __forceinline__ f32x4 mfma16(s4v a, s4v b, f32x4 c) {
  return __builtin_amdgcn_mfma_f32_16x16x16bf16_1k(a, b, c, 0, 0, 0);
}
#else
__device__ __forceinline__ f32x4 mfma16(s4v a, s4v b, f32x4 c) {
  f32x4 d;
  asm volatile("v_mfma_f32_16x16x16_bf16 %0, %1, %2, %3"
               : "=v"(d) : "v"(a), "v"(b), "v"(c));
  return d;
}
#endif

__device__ __forceinline__ unsigned short f2bf(float f) {
  union { float f; unsigned u; } v; v.f = f;
  unsigned r = v.u + 0x7fffu + ((v.u >> 16) & 1u);
  return (unsigned short)(r >> 16);
}

__device__ __forceinline__ void async16(const void* g, void* l) {
  typedef const unsigned int __attribute__((address_space(1)))* gas_t;
  typedef unsigned int __attribute__((address_space(3)))* las_t;
  __builtin_amdgcn_global_load_lds((gas_t)(unsigned long long)g,
                                   (las_t)(unsigned)(unsigned long long)l,
                                   16, 0, 0);
}

// ---------------- merged prep: conv_x | weight transpose | rope table ----------------
__global__ __launch_bounds__(256) void k_prep(
    const float* __restrict__ x,
    const float* __restrict__ Wq, const float* __restrict__ Wkv, const float* __restrict__ Wo,
    unsigned short* __restrict__ xb, unsigned short* __restrict__ WqkvT,
    unsigned short* __restrict__ WoT, float2* __restrict__ tab)
{
  __shared__ float tile[64][65];
  const int bx = blockIdx.x, tid = threadIdx.x;
  if (bx < 2048) {
    const float4* x4 = (const float4*)x;
    ushort4* xb4 = (ushort4*)xb;
    const int n4 = (NB_B * NB_N * NB_DIM) / 4;
    for (int i = bx * 256 + tid; i < n4; i += 2048 * 256) {
      float4 v = x4[i];
      ushort4 o;
      o.x = f2bf(v.x); o.y = f2bf(v.y); o.z = f2bf(v.z); o.w = f2bf(v.w);
      xb4[i] = o;
    }
  } else if (bx < 2816) {
    int idx = bx - 2048;
    int z = idx >> 8, rem = idx & 255;
    const float* W; unsigned short* out;
    if (z == 0)      { W = Wq;  out = WqkvT; }
    else if (z == 1) { W = Wkv; out = WqkvT + 1024 * 1024; }
    else             { W = Wo;  out = WoT; }
    int c0 = (rem & 15) * 64, k0 = (rem >> 4) * 64;
    int tx = tid & 63, ty = tid >> 6;
    #pragma unroll
    for (int i = 0; i < 16; ++i) {
      int k = ty + i * 4;
      tile[k][tx] = W[(long)(k0 + k) * 1024 + c0 + tx];
    }
    __syncthreads();
    #pragma unroll
    for (int i = 0; i < 16; ++i) {
      int c = ty + i * 4;
      out[(long)(c0 + c) * 1024 + k0 + tx] = f2bf(tile[tx][c]);
    }
  } else {
    int idx = (bx - 2816) * 256 + tid;   // [0, 131072)
    int n = idx >> 5, fi = idx & 31;
    float inv = exp2f(-(float)fi * (13.287712379549449f / 32.0f));
    float ang = (float)n * inv;
    float s, c;
    sincosf(ang, &s, &c);
    tab[idx] = make_float2(c, s);
  }
}

// ===== shared GEMM core pieces: BK=64, XOR-swizzled LDS =====
// storage As[row][slot] (slot 0..7, 8 shorts each) holds global chunk g = slot ^ (row&7).
// staging: thread (srow=tid>>3, sdc=tid&7) loads global chunk sdc^(srow&7) -> linear dst.
// read: logical chunk c=kc*4+quad at row -> slot c^(row&7).

// ---------------- QKV GEMM with fused rope + scale (q) / rope + LN (kv) ----------------
__global__ __launch_bounds__(256) void k_gemm_qkv(
    const unsigned short* __restrict__ A,
    const unsigned short* __restrict__ Bt,
    unsigned short* __restrict__ qf,
    unsigned short* __restrict__ lkvp,
    const float2* __restrict__ tab,
    const float* __restrict__ ln_g,
    const float* __restrict__ ln_b)
{
  __shared__ unsigned short As[128 * 64];
  __shared__ unsigned short Bs[128 * 64];
  const int tid = threadIdx.x;
  const int w = tid >> 6, lane = tid & 63;
  const int wr = w >> 1, wc = w & 1;
  const int quad = lane >> 4, l15 = lane & 15;
  const long tm = (long)blockIdx.y * 128, tn = (long)blockIdx.x * 128;
  const int K = 1024;

  f32x4 acc[4][4];
  #pragma unroll
  for (int i = 0; i < 4; ++i)
    #pragma unroll
    for (int j = 0; j < 4; ++j)
      acc[i][j] = (f32x4){0.f, 0.f, 0.f, 0.f};

  const int srow = tid >> 3, sdc = tid & 7;
  const int g8 = sdc ^ (srow & 7);
  const unsigned short* Ag = A + (tm + srow) * K + g8 * 8;
  const unsigned short* Bg = Bt + (tn + srow) * K + g8 * 8;
  unsigned short* Al = &As[srow * 64 + sdc * 8];
  unsigned short* Bl = &Bs[srow * 64 + sdc * 8];

  for (int k0 = 0; k0 < K; k0 += 64) {
    __syncthreads();
    #pragma unroll
    for (int p = 0; p < 4; ++p) {
      async16(Ag + (long)(p * 32) * K + k0, Al + p * 2048);
      async16(Bg + (long)(p * 32) * K + k0, Bl + p * 2048);
    }
    __syncthreads();
    #pragma unroll
    for (int kc = 0; kc < 2; ++kc) {
      short8 af[4], bfr[4];
      #pragma unroll
      for (int i = 0; i < 4; ++i) {
        const int row = wr * 64 + i * 16 + l15;
        af[i] = *(const short8*)&As[row * 64 + (((kc * 4 + quad) ^ (row & 7)) * 8)];
      }
      #pragma unroll
      for (int j = 0; j < 4; ++j) {
        const int row = wc * 64 + j * 16 + l15;
        bfr[j] = *(const short8*)&Bs[row * 64 + (((kc * 4 + quad) ^ (row & 7)) * 8)];
      }
      #pragma unroll
      for (int i = 0; i < 4; ++i)
        #pragma unroll
        for (int j = 0; j < 4; ++j)
          acc[i][j] = __builtin_amdgcn_mfma_f32_16x16x32_bf16(af[i], bfr[j], acc[i][j], 0, 0, 0);
    }
  }

  const int col_base = (int)tn + wc * 64;
  const bool is_q = col_base < 1024;
  const int hh = (col_base & 1023) >> 6;
  unsigned short* dst = is_q ? qf : lkvp;
  float g_ln[4], b_ln[4];
  #pragma unroll
  for (int j = 0; j < 4; ++j) { g_ln[j] = ln_g[j * 16 + l15]; b_ln[j] = ln_b[j * 16 + l15]; }

  const int row_base = (int)tm + wr * 64;
  #pragma unroll
  for (int i = 0; i < 4; ++i) {
    #pragma unroll
    for (int r = 0; r < 4; ++r) {
      const int row = row_base + i * 16 + quad * 4 + r;
      const int n = row & 4095, b = row >> 12;
      const float2 cs0 = tab[n * 32 + l15];
      const float2 cs1 = tab[n * 32 + 16 + l15];
      float val[4];
      #pragma unroll
      for (int j = 0; j < 4; ++j) {
        float t = acc[i][j][r], pt = acc[i][j ^ 2][r];
        float2 cs = (j & 1) ? cs1 : cs0;
        float rot = (j < 2) ? -pt : pt;
        val[j] = t * cs.x + rot * cs.y;
      }
      unsigned short* orow = dst + ((long)(b * 16 + hh) * NB_N + n) * 64;
      if (is_q) {
        #pragma unroll
        for (int j = 0; j < 4; ++j)
          orow[j * 16 + l15] = f2bf(val[j] * QSCALE);
      } else {
        float s = val[0] + val[1] + val[2] + val[3];
        #pragma unroll
        for (int o = 1; o < 16; o <<= 1) s += __shfl_xor(s, o);
        const float mu = s * 0.015625f;
        float dv[4], vs = 0.f;
        #pragma unroll
        for (int j = 0; j < 4; ++j) { dv[j] = val[j] - mu; vs += dv[j] * dv[j]; }
        #pragma unroll
        for (int o = 1; o < 16; o <<= 1) vs += __shfl_xor(vs, o);
        const float rr = rsqrtf(vs * 0.015625f + 1e-5f);
        #pragma unroll
        for (int j = 0; j < 4; ++j)
          orow[j * 16 + l15] = f2bf(dv[j] * rr * g_ln[j] + b_ln[j]);
      }
    }
  }
}

// ---------------- generic bf16 GEMM (final projection), BK=64 swizzled ----------------
__global__ __launch_bounds__(256) void k_gemm_bt(
    const unsigned short* __restrict__ A,
    const unsigned short* __restrict__ Bt,
    float* __restrict__ C,
    const float* __restrict__ bias,
    int K, int ldc)
{
  __shared__ unsigned short As[128 * 64];
  __shared__ unsigned short Bs[128 * 64];
  const int tid = threadIdx.x;
  const int w = tid >> 6, lane = tid & 63;
  const int wr = w >> 1, wc = w & 1;
  const int quad = lane >> 4, l15 = lane & 15;
  const long tm = (long)blockIdx.y * 128, tn = (long)blockIdx.x * 128;

  f32x4 acc[4][4];
  #pragma unroll
  for (int i = 0; i < 4; ++i)
    #pragma unroll
    for (int j = 0; j < 4; ++j)
      acc[i][j] = (f32x4){0.f, 0.f, 0.f, 0.f};

  const int srow = tid >> 3, sdc = tid & 7;
  const int g8 = sdc ^ (srow & 7);
  const unsigned short* Ag = A + (tm + srow) * K + g8 * 8;
  const unsigned short* Bg = Bt + (tn + srow) * K + g8 * 8;
  unsigned short* Al = &As[srow * 64 + sdc * 8];
  unsigned short* Bl = &Bs[srow * 64 + sdc * 8];

  for (int k0 = 0; k0 < K; k0 += 64) {
    __syncthreads();
    #pragma unroll
    for (int p = 0; p < 4; ++p) {
      async16(Ag + (long)(p * 32) * K + k0, Al + p * 2048);
      async16(Bg + (long)(p * 32) * K + k0, Bl + p * 2048);
    }
    __syncthreads();
    #pragma unroll
    for (int kc = 0; kc < 2; ++kc) {
      short8 af[4], bfr[4];
      #pragma unroll
      for (int i = 0; i < 4; ++i) {
        const int row = wr * 64 + i * 16 + l15;
        af[i] = *(const short8*)&As[row * 64 + (((kc * 4 + quad) ^ (row & 7)) * 8)];
      }
      #pragma unroll
      for (int j = 0; j < 4; ++j) {
        const int row = wc * 64 + j * 16 + l15;
        bfr[j] = *(const short8*)&Bs[row * 64 + (((kc * 4 + quad) ^ (row & 7)) * 8)];
      }
      #pragma unroll
      for (int i = 0; i < 4; ++i)
        #pragma unroll
        for (int j = 0; j < 4; ++j)
          acc[i][j] = __builtin_amdgcn_mfma_f32_16x16x32_bf16(af[i], bfr[j], acc[i][j], 0, 0, 0);
    }
  }

  #pragma unroll
  for (int j = 0; j < 4; ++j) {
    const long col = tn + wc * 64 + j * 16 + l15;
    const float bv = bias ? bias[col] : 0.0f;
    #pragma unroll
    for (int i = 0; i < 4; ++i) {
      #pragma unroll
      for (int r = 0; r < 4; ++r) {
        const long row = tm + wr * 64 + i * 16 + quad * 4 + r;
        C[row * ldc + col] = acc[i][j][r] + bv;
      }
    }
  }
}

// ---------------- flash attention: S^T/O^T, 18.4KB LDS, deferred-max softmax ----------------
__global__ __launch_bounds__(256) void k_attn(
    const unsigned short* __restrict__ qf,
    const unsigned short* __restrict__ lkv,
    unsigned short* __restrict__ attn_out,
    float* __restrict__ Opart,      // transposed: [(s,qb)][d(64)][q(128)]
    float* __restrict__ mpart,
    float* __restrict__ lpart)
{
  __shared__ unsigned short smem[9216];   // 18432 B
  unsigned short* Ks = smem;              // [64][72]
  unsigned short* Vt = smem + 4608;       // [64][72], [d][key ^ (d&56)]

  const int tid = threadIdx.x;
  const int w = tid >> 6, lane = tid & 63;
  const int quad = lane >> 4, l15 = lane & 15;

  const int bx = blockIdx.x;
  int bh, q0tok, kstart, kt0, kt1, q0lat, s6 = 0, qb = 0;
  bool latent;
  if (bx < 256 * NSPLIT) {
    latent = true;
    qb = bx / NSPLIT;            // bh*8 + qt
    s6 = bx % NSPLIT;
    bh = qb >> 3;
    q0lat = (qb & 7) * 128;
    q0tok = NB_CTX + q0lat;
    kstart = 0;
    int nkt = (NB_CTX + q0lat + 128) >> 6;
    kt0 = (s6 * nkt) / NSPLIT;
    kt1 = ((s6 + 1) * nkt) / NSPLIT;
  } else {
    latent = false;
    int idx = bx - 256 * NSPLIT;
    bh = idx / 24;
    int r2 = idx % 24;
    int seg = r2 >> 1;
    q0lat = 0;
    q0tok = seg * 256 + (r2 & 1) * 128;
    kstart = seg * 256;
    kt0 = 0; kt1 = 4;
  }

  const unsigned short* qbase = qf + ((long)bh * NB_N + q0tok) * 64;
  const unsigned short* kbase = lkv + (long)bh * NB_N * 64;

  // Q fragments direct from global
  short8 qfr[2][2];
  #pragma unroll
  for (int qg = 0; qg < 2; ++qg)
    #pragma unroll
    for (int kc = 0; kc < 2; ++kc)
      qfr[qg][kc] = *(const short8*)(qbase + (w * 32 + qg * 16 + l15) * 64 + kc * 32 + quad * 8);

  const int kp = tid >> 3, sdc = tid & 7;

  uint4 gA, gB;
  {
    const int key0 = kstart + kt0 * 64;
    gA = *(const uint4*)(kbase + (long)(key0 + 2 * kp) * 64 + sdc * 8);
    gB = *(const uint4*)(kbase + (long)(key0 + 2 * kp + 1) * 64 + sdc * 8);
  }

  f32x4 ot[2][4];     // O^T in 2^-mi units
  float mi[2], li[2];
  #pragma unroll
  for (int qg = 0; qg < 2; ++qg) {
    #pragma unroll
    for (int dt = 0; dt < 4; ++dt) ot[qg][dt] = (f32x4){0.f, 0.f, 0.f, 0.f};
    mi[qg] = 0.f; li[qg] = 0.f;
  }

  for (int kt = kt0; kt < kt1; ++kt) {
    const int key0 = kstart + kt * 64;
    __syncthreads();
    *(uint4*)&Ks[(2 * kp) * 72 + sdc * 8] = gA;
    *(uint4*)&Ks[(2 * kp + 1) * 72 + sdc * 8] = gB;
    {
      const unsigned short* eA = (const unsigned short*)&gA;
      const unsigned short* eB = (const unsigned short*)&gB;
      #pragma unroll
      for (int j = 0; j < 8; ++j) {
        const int d = sdc * 8 + j;
        const unsigned int pair = (unsigned int)eA[j] | ((unsigned int)eB[j] << 16);
        *(unsigned int*)&Vt[d * 72 + ((2 * kp) ^ (d & 56))] = pair;
      }
    }
    __syncthreads();
    if (kt + 1 < kt1) {
      const int key0n = key0 + 64;
      gA = *(const uint4*)(kbase + (long)(key0n + 2 * kp) * 64 + sdc * 8);
      gB = *(const uint4*)(kbase + (long)(key0n + 2 * kp + 1) * 64 + sdc * 8);
    }

    // S^T[key][q]
    f32x4 st[2][4];
    #pragma unroll
    for (int qg = 0; qg < 2; ++qg)
      #pragma unroll
      for (int k4 = 0; k4 < 4; ++k4)
        st[qg][k4] = (f32x4){0.f, 0.f, 0.f, 0.f};
    #pragma unroll
    for (int kc = 0; kc < 2; ++kc) {
      short8 kf[4];
      #pragma unroll
      for (int k4 = 0; k4 < 4; ++k4)
        kf[k4] = *(const short8*)&Ks[(k4 * 16 + l15) * 72 + kc * 32 + quad * 8];
      #pragma unroll
      for (int qg = 0; qg < 2; ++qg)
        #pragma unroll
        for (int k4 = 0; k4 < 4; ++k4)
          st[qg][k4] = __builtin_amdgcn_mfma_f32_16x16x32_bf16(kf[k4], qfr[qg][kc], st[qg][k4], 0, 0, 0);
    }

    if (latent && key0 + 63 >= NB_CTX) {
      #pragma unroll
      for (int qg = 0; qg < 2; ++qg) {
        const int qrow = q0lat + w * 32 + qg * 16 + l15;
        #pragma unroll
        for (int k4 = 0; k4 < 4; ++k4)
          #pragma unroll
          for (int r = 0; r < 4; ++r) {
            const int kl = key0 + k4 * 16 + quad * 4 + r - NB_CTX;
            if (kl > qrow) st[qg][k4][r] = NEGF;
          }
      }
    }

    // deferred-max softmax vs previous reference mi
    unsigned int pk[2][4][2];
    float tmx[2], trs[2];
    #pragma unroll
    for (int qg = 0; qg < 2; ++qg) {
      float rs = 0.f;
      float mx = st[qg][0][0];
      #pragma unroll
      for (int k4 = 0; k4 < 4; ++k4) {
        unsigned int b[4];
        #pragma unroll
        for (int r = 0; r < 4; ++r) {
          mx = fmaxf(mx, st[qg][k4][r]);
          float p = __builtin_amdgcn_exp2f(st[qg][k4][r] - mi[qg]);
          unsigned int pb = __float_as_uint(p) & 0xffff0000u;   // bf16-truncate
          rs += __uint_as_float(pb);
          b[r] = pb;
        }
        pk[qg][k4][0] = __builtin_amdgcn_perm(b[1], b[0], 0x07060302);
        pk[qg][k4][1] = __builtin_amdgcn_perm(b[3], b[2], 0x07060302);
      }
      tmx[qg] = mx; trs[qg] = rs;
    }

    // O^T += V^T P^T
    #pragma unroll
    for (int k4 = 0; k4 < 4; ++k4) {
      s4v vf[4];
      const int kb = k4 * 16 + quad * 4;
      #pragma unroll
      for (int dt = 0; dt < 4; ++dt) {
        const int row = dt * 16 + l15;
        vf[dt] = *(const s4v*)&Vt[row * 72 + (kb ^ (row & 56))];
      }
      #pragma unroll
      for (int qg = 0; qg < 2; ++qg) {
        s4v pf;
        ((unsigned int*)&pf)[0] = pk[qg][k4][0];
        ((unsigned int*)&pf)[1] = pk[qg][k4][1];
        #pragma unroll
        for (int dt = 0; dt < 4; ++dt)
          ot[qg][dt] = mfma16(vf[dt], pf, ot[qg][dt]);
      }
    }

    // update reference; ballot-skip the O rescale when all lanes stable (c==1)
    float cc[2];
    #pragma unroll
    for (int qg = 0; qg < 2; ++qg) {
      float rs = trs[qg];
      rs += __shfl_xor(rs, 16);
      rs += __shfl_xor(rs, 32);
      float mx = tmx[qg];
      mx = fmaxf(mx, __shfl_xor(mx, 16));
      mx = fmaxf(mx, __shfl_xor(mx, 32));
      const float mnew = fmaxf(mi[qg], mx);
      const float c = __builtin_amdgcn_exp2f(mi[qg] - mnew);
      mi[qg] = mnew;
      li[qg] = (li[qg] + rs) * c;
      cc[qg] = c;
    }
    if (__ballot((cc[0] != 1.0f) | (cc[1] != 1.0f))) {
      #pragma unroll
      for (int qg = 0; qg < 2; ++qg)
        #pragma unroll
        for (int dt = 0; dt < 4; ++dt) {
          ot[qg][dt][0] *= cc[qg]; ot[qg][dt][1] *= cc[qg];
          ot[qg][dt][2] *= cc[qg]; ot[qg][dt][3] *= cc[qg];
        }
    }
  }

  __syncthreads();
  if (latent) {
    const long pb = (long)(s6 * 256 + qb);
    if (quad == 0) {
      #pragma unroll
      for (int qg = 0; qg < 2; ++qg) {
        mpart[pb * 128 + w * 32 + qg * 16 + l15] = mi[qg];
        lpart[pb * 128 + w * 32 + qg * 16 + l15] = li[qg];
      }
    }
    float* obase = Opart + pb * 8192;
    #pragma unroll
    for (int qg = 0; qg < 2; ++qg) {
      const int q = w * 32 + qg * 16 + l15;
      #pragma unroll
      for (int dt = 0; dt < 4; ++dt)
        #pragma unroll
        for (int r = 0; r < 4; ++r)
          obase[(dt * 16 + quad * 4 + r) * 128 + q] = ot[qg][dt][r];
    }
  } else {
    #pragma unroll
    for (int qg = 0; qg < 2; ++qg) {
      const float inv = 1.0f / li[qg];
      const int q = w * 32 + qg * 16 + l15;
      #pragma unroll
      for (int dt = 0; dt < 4; ++dt)
        #pragma unroll
        for (int r = 0; r < 4; ++r)
          smem[q * 72 + dt * 16 + quad * 4 + r] = f2bf(ot[qg][dt][r] * inv);
    }
    __syncthreads();
    const int qrow = tid >> 1, half = tid & 1;
    const int b_ = bh >> 4, h_ = bh & 15;
    unsigned short* orow = attn_out + ((long)b_ * NB_N + q0tok + qrow) * NB_DIM + h_ * 64 + half * 32;
    #pragma unroll
    for (int v = 0; v < 4; ++v)
      *(uint4*)(orow + v * 8) = *(const uint4*)&smem[qrow * 72 + half * 32 + v * 8];
  }
}

// ---------------- combine latent split-K partials (transposed Opart layout) ----------------
__global__ __launch_bounds__(256) void k_combine(
    const float* __restrict__ Opart, const float* __restrict__ mpart,
    const float* __restrict__ lpart, unsigned short* __restrict__ attn_out)
{
  __shared__ unsigned short lds[9216];   // [128][72] bf16
  const int qb = blockIdx.x;             // bh*8 + qt
  const int bh = qb >> 3, qt = qb & 7;
  const int b = bh >> 4, h = bh & 15;
  const int t = threadIdx.x;
  const int qq = t & 31;                 // q = qq*4 + qi
  const int dg = t >> 5;                 // d = dg*8 .. +7

  float m[NSPLIT][4], l[NSPLIT][4];
  float mstar[4];
  #pragma unroll
  for (int qi = 0; qi < 4; ++qi) mstar[qi] = NEGF;
  #pragma unroll
  for (int s = 0; s < NSPLIT; ++s) {
    #pragma unroll
    for (int qi = 0; qi < 4; ++qi) {
      m[s][qi] = mpart[(s * 256 + qb) * 128 + qq * 4 + qi];
      l[s][qi] = lpart[(s * 256 + qb) * 128 + qq * 4 + qi];
      mstar[qi] = fmaxf(mstar[qi], m[s][qi]);
    }
  }
  float inv[4];
  #pragma unroll
  for (int qi = 0; qi < 4; ++qi) {
    float lsum = 0.f;
    #pragma unroll
    for (int s = 0; s < NSPLIT; ++s)
      lsum += __builtin_amdgcn_exp2f(m[s][qi] - mstar[qi]) * l[s][qi];
    inv[qi] = 1.0f / lsum;
  }

  float o[8][4];
  #pragma unroll
  for (int dd = 0; dd < 8; ++dd)
    #pragma unroll
    for (int qi = 0; qi < 4; ++qi) o[dd][qi] = 0.f;
  #pragma unroll
  for (int s = 0; s < NSPLIT; ++s) {
    float wgt[4];
    #pragma unroll
    for (int qi = 0; qi < 4; ++qi)
      wgt[qi] = __builtin_amdgcn_exp2f(m[s][qi] - mstar[qi]);
    const float* base = Opart + (long)(s * 256 + qb) * 8192;
    #pragma unroll
    for (int dd = 0; dd < 8; ++dd) {
      float4 v = *(const float4*)(base + (dg * 8 + dd) * 128 + qq * 4);
      o[dd][0] += wgt[0] * v.x; o[dd][1] += wgt[1] * v.y;
      o[dd][2] += wgt[2] * v.z; o[dd][3] += wgt[3] * v.w;
    }
  }
  #pragma unroll
  for (int qi = 0; qi < 4; ++qi) {
    ushort4 u0, u1;
    u0.x = f2bf(o[0][qi] * inv[qi]); u0.y = f2bf(o[1][qi] * inv[qi]);
    u0.z = f2bf(o[2][qi] * inv[qi]); u0.w = f2bf(o[3][qi] * inv[qi]);
    u1.x = f2bf(o[4][qi] * inv[qi]); u1.y = f2bf(o[5][qi] * inv[qi]);
    u1.z = f2bf(o[6][qi] * inv[qi]); u1.w = f2bf(o[7][qi] * inv[qi]);
    *(ushort4*)&lds[(qq * 4 + qi) * 72 + dg * 8] = u0;
    *(ushort4*)&lds[(qq * 4 + qi) * 72 + dg * 8 + 4] = u1;
  }
  __syncthreads();
  const int qrow = t >> 1, half = t & 1;
  unsigned short* orow = attn_out + ((long)b * NB_N + NB_CTX + qt * 128 + qrow) * NB_DIM + h * 64 + half * 32;
  #pragma unroll
  for (int v = 0; v < 4; ++v)
    *(uint4*)(orow + v * 8) = *(const uint4*)&lds[qrow * 72 + half * 32 + v * 8];
}

extern "C" void kernel_launch(void* const* d_in, const int* in_sizes, int n_in,
                              void* d_out, int out_size, void* d_ws, size_t ws_size,
                              hipStream_t stream)
{
  const float* x    = (const float*)d_in[0];
  const float* Wq   = (const float*)d_in[1];
  const float* Wkv  = (const float*)d_in[2];
  const float* Wo   = (const float*)d_in[3];
  const float* bo   = (const float*)d_in[4];
  const float* ln_g = (const float*)d_in[5];
  const float* ln_b = (const float*)d_in[6];
  float* out = (float*)d_out;

  char* ws = (char*)d_ws;
  unsigned short* xb    = (unsigned short*)(ws);                       // [0,16M)
  unsigned short* WqkvT = (unsigned short*)(ws + (size_t)(16 << 20));  // [16,20M)
  unsigned short* WoT   = (unsigned short*)(ws + (size_t)(20 << 20));  // [20,22M)
  float2*         tab   = (float2*)        (ws + (size_t)(22 << 20));  // [22,23M)
  unsigned short* qfb   = (unsigned short*)(ws + (size_t)(24 << 20));  // [24,40M)
  unsigned short* lkv   = (unsigned short*)(ws + (size_t)(40 << 20));  // [40,56M)
  unsigned short* aout  = (unsigned short*)(ws + (size_t)(56 << 20));  // [56,72M)
  float*          Opart = (float*)         (ws + (size_t)(72 << 20));  // [72,106M)
  float*          mpart = (float*)         (ws + (size_t)(112 << 20)); // [112,113M)
  float*          lpart = (float*)         (ws + (size_t)(113 << 20)); // [113,114M)

  hipLaunchKernelGGL(k_prep, dim3(3328), dim3(256), 0, stream,
                     x, Wq, Wkv, Wo, xb, WqkvT, WoT, tab);
  hipLaunchKernelGGL(k_gemm_qkv, dim3(16, 64), dim3(256), 0, stream,
                     xb, WqkvT, qfb, lkv, tab, ln_g, ln_b);
  hipLaunchKernelGGL(k_attn, dim3(256 * NSPLIT + 768), dim3(256), 0, stream,
                     qfb, lkv, aout, Opart, mpart, lpart);
  hipLaunchKernelGGL(k_combine, dim3(256), dim3(256), 0, stream,
                     Opart, mpart, lpart, aout);
  hipLaunchKernelGGL(k_gemm_bt, dim3(8, 64), dim3(256), 0, stream,
                     aout, WoT, out, bo, 1024, 1024);
}